// Round 9
// baseline (468.062 us; speedup 1.0000x reference)
//
#include <hip/hip_runtime.h>

// Attention block: x_s = softmax(qk^T)[:4096,4096:] @ query @ Wps^T
//                  x_q = softmax(qk^T)[4096:,:4096] @ s     @ Wpq^T
// R9 = R8 + launch-graph packing:
//  - GEMM1 (qk projection) and the V'^T pair merged into ONE 1536-block
//    launch (exactly 2 block-generations at 3 blocks/CU; kills GEMM1's
//    1.33-generation tail + one launch gap). Shared K=1024 loop, unified
//    epilogue outb = bf16(acc*sc).
//  - rowsum zeroing folded into prep_all (drops the memset dispatch).
// Core GEMM unchanged from R8: 16x16x32 bf16 MFMA, 128x128/4-wave,
// XOR-swizzled LDS staging (conflicts == 0), hoisted frag offsets,
// exp->2^x fold (LOG2E in q-scale), re-associated PV writes fp32 to d_out.

typedef unsigned short u16;
typedef __bf16 bf16x8 __attribute__((ext_vector_type(8)));
typedef float f32x4 __attribute__((ext_vector_type(4)));
typedef unsigned short u16x8 __attribute__((ext_vector_type(8)));

#define DEVI static __device__ __forceinline__

DEVI u16 f2b(float f) {  // fp32 -> bf16 round-to-nearest-even
  unsigned int u = __float_as_uint(f);
  u += 0x7fffu + ((u >> 16) & 1u);
  return (u16)(u >> 16);
}

DEVI float exp2_hw(float x) {  // v_exp_f32: 2^x
  float r;
  asm("v_exp_f32 %0, %1" : "=v"(r) : "v"(x));
  return r;
}

// ---------------- fused prep ----------------
// [0,4096):    cB rows (s+tg | query), sBf = bf16(s) for rows<4096
// [4096,5120): Wqkv q,k rows -> WqkB
// [5120,5632): Wps -> WpsB ; [5632,6144): Wpq -> WpqB
// [6144,6152): rowsum = 0
__global__ void prep_all(const float* __restrict__ query, const float* __restrict__ s,
                         const float* __restrict__ tg, const float* __restrict__ w0,
                         const float* __restrict__ w1, const float* __restrict__ w2,
                         u16* __restrict__ cB, u16* __restrict__ sBf,
                         u16* __restrict__ o0, u16* __restrict__ o1,
                         u16* __restrict__ o2, float* __restrict__ rowsum) {
  int b = blockIdx.x;
  if (b >= 6144) {
    rowsum[(b - 6144) * 1024 + (int)threadIdx.x * 4 + 0] = 0.f;
    rowsum[(b - 6144) * 1024 + (int)threadIdx.x * 4 + 1] = 0.f;
    rowsum[(b - 6144) * 1024 + (int)threadIdx.x * 4 + 2] = 0.f;
    rowsum[(b - 6144) * 1024 + (int)threadIdx.x * 4 + 3] = 0.f;
    return;
  }
  if (b < 4096) {
    int base = (b * 256 + threadIdx.x) << 3;
    int row = base >> 10;
    u16x8 o;
    if (row < 4096) {
      float4 a0 = *(const float4*)(s + base);
      float4 a1 = *(const float4*)(s + base + 4);
      float4 b0 = *(const float4*)(tg + base);
      float4 b1 = *(const float4*)(tg + base + 4);
      u16x8 os;
      os[0] = f2b(a0.x); os[1] = f2b(a0.y); os[2] = f2b(a0.z); os[3] = f2b(a0.w);
      os[4] = f2b(a1.x); os[5] = f2b(a1.y); os[6] = f2b(a1.z); os[7] = f2b(a1.w);
      *(u16x8*)(sBf + base) = os;
      o[0] = f2b(a0.x + b0.x); o[1] = f2b(a0.y + b0.y);
      o[2] = f2b(a0.z + b0.z); o[3] = f2b(a0.w + b0.w);
      o[4] = f2b(a1.x + b1.x); o[5] = f2b(a1.y + b1.y);
      o[6] = f2b(a1.z + b1.z); o[7] = f2b(a1.w + b1.w);
    } else {
      int qb = base - 4096 * 1024;
      float4 a0 = *(const float4*)(query + qb);
      float4 a1 = *(const float4*)(query + qb + 4);
      o[0] = f2b(a0.x); o[1] = f2b(a0.y); o[2] = f2b(a0.z); o[3] = f2b(a0.w);
      o[4] = f2b(a1.x); o[5] = f2b(a1.y); o[6] = f2b(a1.z); o[7] = f2b(a1.w);
    }
    *(u16x8*)(cB + base) = o;
  } else {
    const float* in; u16* out; int lb;
    if (b < 5120)      { in = w0; out = o0; lb = b - 4096; }
    else if (b < 5632) { in = w1; out = o1; lb = b - 5120; }
    else               { in = w2; out = o2; lb = b - 5632; }
    int base = (lb * 256 + threadIdx.x) << 3;
    float4 a0 = *(const float4*)(in + base);
    float4 a1 = *(const float4*)(in + base + 4);
    u16x8 o;
    o[0] = f2b(a0.x); o[1] = f2b(a0.y); o[2] = f2b(a0.z); o[3] = f2b(a0.w);
    o[4] = f2b(a1.x); o[5] = f2b(a1.y); o[6] = f2b(a1.z); o[7] = f2b(a1.w);
    *(u16x8*)(out + base) = o;
  }
}

// ---------------- merged GEMM1 + V'^T: C = A[M,1024] @ B[N,1024]^T ----------
// blocks [0,1024):    qks = cB @ WqkB^T  (bx=b&15, by=b>>4; ldc 2048)
//   scale: col<1024 -> SCALE*LOG2E (q), else SCALE (k)
// blocks [1024,1536): V'z = Wproj_z @ input_z^T  (ldc 4096, scale 1)
__global__ __launch_bounds__(256)
void gemm_qkv(const u16* __restrict__ cB, const u16* __restrict__ WqkB,
              u16* __restrict__ qks,
              const u16* __restrict__ WpsB, const u16* __restrict__ WpqB,
              const u16* __restrict__ qBf, const u16* __restrict__ sBf,
              u16* __restrict__ VsT, u16* __restrict__ VqT,
              float sq, float sk) {
  __shared__ __align__(16) u16 sA[128 * 64];
  __shared__ __align__(16) u16 sB[128 * 64];
  const int b = blockIdx.x;
  const u16* Ap; const u16* Bp; u16* op;
  int bx, by, ldc;
  bool proj;
  if (b < 1024) {
    proj = true;  bx = b & 15; by = b >> 4;
    Ap = cB; Bp = WqkB; op = qks; ldc = 2048;
  } else {
    proj = false;
    int b2 = b - 1024;
    int z = b2 >> 8, rem = b2 & 255;
    bx = rem & 31; by = rem >> 5;
    Ap = z ? WpqB : WpsB; Bp = z ? sBf : qBf; op = z ? VqT : VsT; ldc = 4096;
  }
  const int tid = threadIdx.x;
  const int lane = tid & 63;
  const int wave = tid >> 6;
  const int wr = (wave >> 1) * 64;
  const int wc = (wave & 1) * 64;
  const int ar = lane & 15;

  const u16* Ab = Ap + (size_t)(by * 128) * 1024;
  const u16* Bb = Bp + (size_t)(bx * 128) * 1024;

  f32x4 zero = {0.0f, 0.0f, 0.0f, 0.0f};
  f32x4 acc[4][4];
#pragma unroll
  for (int i = 0; i < 4; ++i)
#pragma unroll
    for (int j = 0; j < 4; ++j) acc[i][j] = zero;

  const int sr = tid >> 3;
  const int scL = (tid & 7) << 3;
  const int scG = ((tid & 7) ^ (sr & 7)) << 3;

  const int l7 = lane & 7, l16 = lane >> 4;
  const int p0b = (l16 ^ l7) << 4;
  const int offA0 = (wr + ar) * 128 + p0b;
  const int offB0 = (wc + ar) * 128 + p0b;
  const char* sAc = (const char*)sA;
  const char* sBc = (const char*)sB;

  for (int k0 = 0; k0 < 1024; k0 += 64) {
#pragma unroll
    for (int it = 0; it < 4; ++it) {
      int r = it * 32 + sr;
      __builtin_amdgcn_global_load_lds(
          (__attribute__((address_space(1))) void*)(Ab + (size_t)r * 1024 + k0 + scG),
          (__attribute__((address_space(3))) void*)(sA + r * 64 + scL), 16, 0, 0);
    }
#pragma unroll
    for (int it = 0; it < 4; ++it) {
      int r = it * 32 + sr;
      __builtin_amdgcn_global_load_lds(
          (__attribute__((address_space(1))) void*)(Bb + (size_t)r * 1024 + k0 + scG),
          (__attribute__((address_space(3))) void*)(sB + r * 64 + scL), 16, 0, 0);
    }
    __syncthreads();
#pragma unroll
    for (int half = 0; half < 2; ++half) {
      const int px = half ? 64 : 0;
      bf16x8 af[4], bfr[4];
#pragma unroll
      for (int t = 0; t < 4; ++t)
        af[t] = *(const bf16x8*)(sAc + ((offA0 ^ px) + t * 2048));
#pragma unroll
      for (int t = 0; t < 4; ++t)
        bfr[t] = *(const bf16x8*)(sBc + ((offB0 ^ px) + t * 2048));
#pragma unroll
      for (int tm = 0; tm < 4; ++tm)
#pragma unroll
        for (int tn = 0; tn < 4; ++tn)
          acc[tm][tn] = __builtin_amdgcn_mfma_f32_16x16x32_bf16(
              af[tm], bfr[tn], acc[tm][tn], 0, 0, 0);
    }
    __syncthreads();
  }

  const int qr = (lane >> 4) * 4;
  const int qc = lane & 15;
#pragma unroll
  for (int tm = 0; tm < 4; ++tm)
#pragma unroll
    for (int r = 0; r < 4; ++r) {
      int row = by * 128 + wr + tm * 16 + qr + r;
#pragma unroll
      for (int tn = 0; tn < 4; ++tn) {
        int col = bx * 128 + wc + tn * 16 + qc;
        float sc = proj ? ((col < 1024) ? sq : sk) : 1.0f;
        op[(size_t)row * ldc + col] = f2b(acc[tm][tn][r] * sc);
      }
    }
}

// ---------------- 128x128-tile GEMM, 4 waves: C[M,N] = A[M,K] @ B[N,K]^T ----
// EPI 1: 2^acc, quadrant scalar store, rowsum atomics  (scores)
// EPI 4: outf = acc / rs[row]  (fp32, z-batched)       (PV -> d_out)

template <int EPI>
__global__ __launch_bounds__(256)
void gemm_bt(const u16* __restrict__ A, const u16* __restrict__ A1,
             const u16* __restrict__ B, const u16* __restrict__ B1,
             int lda, int ldb, int K, int ldc,
             float* __restrict__ outf, float* __restrict__ outf1,
             const float* __restrict__ rs, const float* __restrict__ rs1,
             u16* __restrict__ Pcq, u16* __restrict__ Pqc,
             float* __restrict__ rowsum) {
  __shared__ __align__(16) u16 sA[128 * 64];
  __shared__ __align__(16) u16 sB[128 * 64];
  const int tid = threadIdx.x;
  const int lane = tid & 63;
  const int wave = tid >> 6;
  const int wr = (wave >> 1) * 64;
  const int wc = (wave & 1) * 64;
  const int ar = lane & 15;
  const int by = blockIdx.y, bx = blockIdx.x;
  const int z = blockIdx.z;

  const u16* Ab = (z ? A1 : A) + (size_t)(by * 128) * lda;
  const u16* Bb = (z ? B1 : B) + (size_t)(bx * 128) * ldb;

  f32x4 zero = {0.0f, 0.0f, 0.0f, 0.0f};
  f32x4 acc[4][4];
#pragma unroll
  for (int i = 0; i < 4; ++i)
#pragma unroll
    for (int j = 0; j < 4; ++j) acc[i][j] = zero;

  const int sr = tid >> 3;
  const int scL = (tid & 7) << 3;
  const int scG = ((tid & 7) ^ (sr & 7)) << 3;

  const int l7 = lane & 7, l16 = lane >> 4;
  const int p0b = (l16 ^ l7) << 4;
  const int offA0 = (wr + ar) * 128 + p0b;
  const int offB0 = (wc + ar) * 128 + p0b;
  const char* sAc = (const char*)sA;
  const char* sBc = (const char*)sB;

  for (int k0 = 0; k0 < K; k0 += 64) {
#pragma unroll
    for (int it = 0; it < 4; ++it) {
      int r = it * 32 + sr;
      __builtin_amdgcn_global_load_lds(
          (__attribute__((address_space(1))) void*)(Ab + (size_t)r * lda + k0 + scG),
          (__attribute__((address_space(3))) void*)(sA + r * 64 + scL), 16, 0, 0);
    }
#pragma unroll
    for (int it = 0; it < 4; ++it) {
      int r = it * 32 + sr;
      __builtin_amdgcn_global_load_lds(
          (__attribute__((address_space(1))) void*)(Bb + (size_t)r * ldb + k0 + scG),
          (__attribute__((address_space(3))) void*)(sB + r * 64 + scL), 16, 0, 0);
    }
    __syncthreads();
#pragma unroll
    for (int half = 0; half < 2; ++half) {
      const int px = half ? 64 : 0;
      bf16x8 af[4], bfr[4];
#pragma unroll
      for (int t = 0; t < 4; ++t)
        af[t] = *(const bf16x8*)(sAc + ((offA0 ^ px) + t * 2048));
#pragma unroll
      for (int t = 0; t < 4; ++t)
        bfr[t] = *(const bf16x8*)(sBc + ((offB0 ^ px) + t * 2048));
#pragma unroll
      for (int tm = 0; tm < 4; ++tm)
#pragma unroll
        for (int tn = 0; tn < 4; ++tn)
          acc[tm][tn] = __builtin_amdgcn_mfma_f32_16x16x32_bf16(
              af[tm], bfr[tn], acc[tm][tn], 0, 0, 0);
    }
    __syncthreads();
  }

  // Epilogue. C/D layout (m89): row=(lane>>4)*4+reg, col=lane&15.
  const int qr = (lane >> 4) * 4;
  const int qc = lane & 15;

  if constexpr (EPI == 1) {
    const bool top = (by < 32);
    const bool left = (bx < 32);
    u16* pdst = nullptr;
    if (top && !left) pdst = Pcq;
    if (!top && left) pdst = Pqc;
    const int growb = by * 128 + wr;
    const int rbase = growb - (top ? 0 : 4096);
    const int cbase = bx * 128 + wc - (left ? 0 : 4096);
#pragma unroll
    for (int tm = 0; tm < 4; ++tm) {
      float e[4][4];
      float rsum[4] = {0.f, 0.f, 0.f, 0.f};
#pragma unroll
      for (int tn = 0; tn < 4; ++tn)
#pragma unroll
        for (int r = 0; r < 4; ++r) {
          e[tn][r] = exp2_hw(acc[tm][tn][r]);  // scores pre-scaled by log2(e)
          rsum[r] += e[tn][r];
        }
#pragma unroll
      for (int r = 0; r < 4; ++r) {
        float v = rsum[r];
        v += __shfl_xor(v, 1);
        v += __shfl_xor(v, 2);
        v += __shfl_xor(v, 4);
        v += __shfl_xor(v, 8);
        if ((lane & 15) == 0)
          atomicAdd(&rowsum[growb + tm * 16 + qr + r], v);
      }
      if (pdst) {
#pragma unroll
        for (int tn = 0; tn < 4; ++tn)
#pragma unroll
          for (int r = 0; r < 4; ++r) {
            int row = rbase + tm * 16 + qr + r;
            pdst[(size_t)row * 4096 + cbase + tn * 16 + qc] = f2b(e[tn][r]);
          }
      }
    }
  } else {  // EPI 4
    float* of = z ? outf1 : outf;
    const float* rsz = z ? rs1 : rs;
#pragma unroll
    for (int tm = 0; tm < 4; ++tm)
#pragma unroll
      for (int r = 0; r < 4; ++r) {
        int row = by * 128 + wr + tm * 16 + qr + r;
        float inv = 1.0f / rsz[row];
#pragma unroll
        for (int tn = 0; tn < 4; ++tn) {
          int col = bx * 128 + wc + tn * 16 + qc;
          of[(size_t)row * ldc + col] = acc[tm][tn][r] * inv;
        }
      }
  }
}

// ---------------- launcher ----------------

extern "C" void kernel_launch(void* const* d_in, const int* in_sizes, int n_in,
                              void* d_out, int out_size, void* d_ws, size_t ws_size,
                              hipStream_t stream) {
  (void)in_sizes; (void)n_in; (void)out_size; (void)ws_size;
  const float* query = (const float*)d_in[0];
  const float* s     = (const float*)d_in[1];
  const float* tg    = (const float*)d_in[2];
  const float* Wqkv  = (const float*)d_in[3];
  const float* Wps   = (const float*)d_in[4];
  const float* Wpq   = (const float*)d_in[5];
  float* out = (float*)d_out;

  char* ws = (char*)d_ws;
  u16* cB     = (u16*)ws; ws += (size_t)8192 * 1024 * 2;   // [s+tg ; query] bf16
  u16* sBf    = (u16*)ws; ws += (size_t)4096 * 1024 * 2;   // s bf16
  u16* qks    = (u16*)ws; ws += (size_t)8192 * 2048 * 2;   // [q*SCALE*LOG2E | k*SCALE]
  u16* WqkB   = (u16*)ws; ws += (size_t)2048 * 1024 * 2;
  u16* WpsB   = (u16*)ws; ws += (size_t)1024 * 1024 * 2;
  u16* WpqB   = (u16*)ws; ws += (size_t)1024 * 1024 * 2;
  u16* VsT    = (u16*)ws; ws += (size_t)1024 * 4096 * 2;   // Wps@query^T
  u16* VqT    = (u16*)ws; ws += (size_t)1024 * 4096 * 2;   // Wpq@s^T
  u16* Pcq    = (u16*)ws; ws += (size_t)4096 * 4096 * 2;
  u16* Pqc    = (u16*)ws; ws += (size_t)4096 * 4096 * 2;
  float* rowsum = (float*)ws;  // 8192 floats

  const u16* qBf = cB + (size_t)4096 * 1024;  // query bf16 rows of cB

  const float SCALE = 0.17677669529663687f;   // 1024^-0.25
  const float LOG2E = 1.4426950408889634f;

  prep_all<<<6152, 256, 0, stream>>>(query, s, tg, Wqkv, Wps, Wpq,
                                     cB, sBf, WqkB, WpsB, WpqB, rowsum);
  // merged GEMM1 + V'^T pair (1536 blocks = 2 full generations at 3 blk/CU)
  gemm_qkv<<<1536, 256, 0, stream>>>(cB, WqkB, qks, WpsB, WpqB, qBf, sBf,
                                     VsT, VqT, SCALE * LOG2E, SCALE);
  // GEMM2: scores (8192x8192) -> 2^score quadrants (bf16) + row sums
  gemm_bt<1><<<dim3(64, 64), 256, 0, stream>>>(
      qks, nullptr, qks + 1024, nullptr, 2048, 2048, 1024, 0,
      nullptr, nullptr, nullptr, nullptr, Pcq, Pqc, rowsum);
  // PV (z-batched), fp32 straight to d_out
  gemm_bt<4><<<dim3(8, 32, 2), 256, 0, stream>>>(
      Pcq, Pqc, VsT, VqT, 4096, 4096, 4096, 1024,
      out, out + (size_t)4096 * 1024, rowsum, rowsum + 4096,
      nullptr, nullptr, nullptr);
}

// Round 10
// 444.621 us; speedup vs baseline: 1.0527x; 1.0527x over previous
//
#include <hip/hip_runtime.h>

// Attention block: x_s = softmax(qk^T)[:4096,4096:] @ query @ Wps^T
//                  x_q = softmax(qk^T)[4096:,:4096] @ s     @ Wpq^T
// R10: 256x128 block tile with 8 waves (512 thr), wave-tile KEPT at 64x64 so
// the K-loop register profile is identical to R8 (80 VGPR, no spill — R4's
// failure was the launch_bounds cap, not the tile). 3 blocks/CU x 8 waves =
// 24 waves/CU (vs 12): 2x latency hiding, half the barriers/FLOP, 0.75x
// staging-writes/FLOP. LDS 48KB. Everything else = R8/R9: 16x16x32 bf16 MFMA,
// XOR-swizzled LDS staging (conflicts 0), hoisted frag offsets, exp->2^x fold,
// re-associated PV (fp32 straight to d_out), merged qkv+V' launch.

typedef unsigned short u16;
typedef __bf16 bf16x8 __attribute__((ext_vector_type(8)));
typedef float f32x4 __attribute__((ext_vector_type(4)));
typedef unsigned short u16x8 __attribute__((ext_vector_type(8)));

#define DEVI static __device__ __forceinline__

DEVI u16 f2b(float f) {  // fp32 -> bf16 round-to-nearest-even
  unsigned int u = __float_as_uint(f);
  u += 0x7fffu + ((u >> 16) & 1u);
  return (u16)(u >> 16);
}

DEVI float exp2_hw(float x) {  // v_exp_f32: 2^x
  float r;
  asm("v_exp_f32 %0, %1" : "=v"(r) : "v"(x));
  return r;
}

// ---------------- fused prep (unchanged from R9) ----------------
__global__ void prep_all(const float* __restrict__ query, const float* __restrict__ s,
                         const float* __restrict__ tg, const float* __restrict__ w0,
                         const float* __restrict__ w1, const float* __restrict__ w2,
                         u16* __restrict__ cB, u16* __restrict__ sBf,
                         u16* __restrict__ o0, u16* __restrict__ o1,
                         u16* __restrict__ o2, float* __restrict__ rowsum) {
  int b = blockIdx.x;
  if (b >= 6144) {
    int i = (b - 6144) * 1024 + (int)threadIdx.x * 4;
    rowsum[i] = 0.f; rowsum[i + 1] = 0.f; rowsum[i + 2] = 0.f; rowsum[i + 3] = 0.f;
    return;
  }
  if (b < 4096) {
    int base = (b * 256 + threadIdx.x) << 3;
    int row = base >> 10;
    u16x8 o;
    if (row < 4096) {
      float4 a0 = *(const float4*)(s + base);
      float4 a1 = *(const float4*)(s + base + 4);
      float4 b0 = *(const float4*)(tg + base);
      float4 b1 = *(const float4*)(tg + base + 4);
      u16x8 os;
      os[0] = f2b(a0.x); os[1] = f2b(a0.y); os[2] = f2b(a0.z); os[3] = f2b(a0.w);
      os[4] = f2b(a1.x); os[5] = f2b(a1.y); os[6] = f2b(a1.z); os[7] = f2b(a1.w);
      *(u16x8*)(sBf + base) = os;
      o[0] = f2b(a0.x + b0.x); o[1] = f2b(a0.y + b0.y);
      o[2] = f2b(a0.z + b0.z); o[3] = f2b(a0.w + b0.w);
      o[4] = f2b(a1.x + b1.x); o[5] = f2b(a1.y + b1.y);
      o[6] = f2b(a1.z + b1.z); o[7] = f2b(a1.w + b1.w);
    } else {
      int qb = base - 4096 * 1024;
      float4 a0 = *(const float4*)(query + qb);
      float4 a1 = *(const float4*)(query + qb + 4);
      o[0] = f2b(a0.x); o[1] = f2b(a0.y); o[2] = f2b(a0.z); o[3] = f2b(a0.w);
      o[4] = f2b(a1.x); o[5] = f2b(a1.y); o[6] = f2b(a1.z); o[7] = f2b(a1.w);
    }
    *(u16x8*)(cB + base) = o;
  } else {
    const float* in; u16* out; int lb;
    if (b < 5120)      { in = w0; out = o0; lb = b - 4096; }
    else if (b < 5632) { in = w1; out = o1; lb = b - 5120; }
    else               { in = w2; out = o2; lb = b - 5632; }
    int base = (lb * 256 + threadIdx.x) << 3;
    float4 a0 = *(const float4*)(in + base);
    float4 a1 = *(const float4*)(in + base + 4);
    u16x8 o;
    o[0] = f2b(a0.x); o[1] = f2b(a0.y); o[2] = f2b(a0.z); o[3] = f2b(a0.w);
    o[4] = f2b(a1.x); o[5] = f2b(a1.y); o[6] = f2b(a1.z); o[7] = f2b(a1.w);
    *(u16x8*)(out + base) = o;
  }
}

// ====== shared K-loop body for 256x128 tile, 8 waves, wave-tile 64x64 ======
// sA: 256 rows x 64 u16 (32 KB), sB: 128 rows x 64 u16 (16 KB).
// Returns acc via reference array. Caller provides Ab (by*256 base), Bb.
struct KLoopOut { f32x4 acc[4][4]; };

DEVI void kloop(const u16* Ab, const u16* Bb, int lda, int ldb, int K,
                u16* sA, u16* sB, int tid, int wr, int wc, f32x4 (&acc)[4][4]) {
  const int lane = tid & 63;
  const int ar = lane & 15;
  const int sr = tid >> 3;                        // 0..63
  const int scL = (tid & 7) << 3;
  const int scG = ((tid & 7) ^ (sr & 7)) << 3;    // swizzled global col granule

  const int l7 = lane & 7, l16 = lane >> 4;
  const int p0b = (l16 ^ l7) << 4;
  const int offA0 = (wr + ar) * 128 + p0b;
  const int offB0 = (wc + ar) * 128 + p0b;
  const char* sAc = (const char*)sA;
  const char* sBc = (const char*)sB;

  for (int k0 = 0; k0 < K; k0 += 64) {
#pragma unroll
    for (int it = 0; it < 4; ++it) {              // A: 256 rows
      int r = it * 64 + sr;
      __builtin_amdgcn_global_load_lds(
          (__attribute__((address_space(1))) void*)(Ab + (size_t)r * lda + k0 + scG),
          (__attribute__((address_space(3))) void*)(sA + r * 64 + scL), 16, 0, 0);
    }
#pragma unroll
    for (int it = 0; it < 2; ++it) {              // B: 128 rows
      int r = it * 64 + sr;
      __builtin_amdgcn_global_load_lds(
          (__attribute__((address_space(1))) void*)(Bb + (size_t)r * ldb + k0 + scG),
          (__attribute__((address_space(3))) void*)(sB + r * 64 + scL), 16, 0, 0);
    }
    __syncthreads();
#pragma unroll
    for (int half = 0; half < 2; ++half) {
      const int px = half ? 64 : 0;
      bf16x8 af[4], bfr[4];
#pragma unroll
      for (int t = 0; t < 4; ++t)
        af[t] = *(const bf16x8*)(sAc + ((offA0 ^ px) + t * 2048));
#pragma unroll
      for (int t = 0; t < 4; ++t)
        bfr[t] = *(const bf16x8*)(sBc + ((offB0 ^ px) + t * 2048));
#pragma unroll
      for (int tm = 0; tm < 4; ++tm)
#pragma unroll
        for (int tn = 0; tn < 4; ++tn)
          acc[tm][tn] = __builtin_amdgcn_mfma_f32_16x16x32_bf16(
              af[tm], bfr[tn], acc[tm][tn], 0, 0, 0);
    }
    __syncthreads();
  }
}

// ---------------- merged GEMM1 + V'^T (512 thr, 256x128 tile) ----------------
// blocks [0,512):   qks = cB @ WqkB^T   (bx=b&15, by=b>>4 in 0..31; ldc 2048)
// blocks [512,768): V'z = Wproj_z @ input_z^T (by 0..3, bx 0..31; ldc 4096)
__global__ __launch_bounds__(512)
void gemm_qkv(const u16* __restrict__ cB, const u16* __restrict__ WqkB,
              u16* __restrict__ qks,
              const u16* __restrict__ WpsB, const u16* __restrict__ WpqB,
              const u16* __restrict__ qBf, const u16* __restrict__ sBf,
              u16* __restrict__ VsT, u16* __restrict__ VqT,
              float sq, float sk) {
  __shared__ __align__(16) u16 sA[256 * 64];
  __shared__ __align__(16) u16 sB[128 * 64];
  const int b = blockIdx.x;
  const u16* Ap; const u16* Bp; u16* op;
  int bx, by, ldc;
  bool proj;
  if (b < 512) {
    proj = true;  bx = b & 15; by = b >> 4;
    Ap = cB; Bp = WqkB; op = qks; ldc = 2048;
  } else {
    proj = false;
    int b2 = b - 512;
    int z = b2 >> 7, rem = b2 & 127;
    bx = rem & 31; by = rem >> 5;
    Ap = z ? WpqB : WpsB; Bp = z ? sBf : qBf; op = z ? VqT : VsT; ldc = 4096;
  }
  const int tid = threadIdx.x;
  const int lane = tid & 63;
  const int wave = tid >> 6;           // 0..7
  const int wr = (wave >> 1) * 64;     // 0,64,128,192
  const int wc = (wave & 1) * 64;      // 0,64

  f32x4 acc[4][4];
#pragma unroll
  for (int i = 0; i < 4; ++i)
#pragma unroll
    for (int j = 0; j < 4; ++j) acc[i][j] = f32x4{0.f, 0.f, 0.f, 0.f};

  kloop(Ap + (size_t)(by * 256) * 1024, Bp + (size_t)(bx * 128) * 1024,
        1024, 1024, 1024, sA, sB, tid, wr, wc, acc);

  const int qr = (lane >> 4) * 4;
  const int qc = lane & 15;
#pragma unroll
  for (int tm = 0; tm < 4; ++tm)
#pragma unroll
    for (int r = 0; r < 4; ++r) {
      int row = by * 256 + wr + tm * 16 + qr + r;
#pragma unroll
      for (int tn = 0; tn < 4; ++tn) {
        int col = bx * 128 + wc + tn * 16 + qc;
        float sc = proj ? ((col < 1024) ? sq : sk) : 1.0f;
        op[(size_t)row * ldc + col] = f2b(acc[tm][tn][r] * sc);
      }
    }
}

// ---------------- scores GEMM (EPI1) and PV GEMM (EPI4), 256x128 tile --------
template <int EPI>
__global__ __launch_bounds__(512)
void gemm_bt(const u16* __restrict__ A, const u16* __restrict__ A1,
             const u16* __restrict__ B, const u16* __restrict__ B1,
             int lda, int ldb, int K, int ldc,
             float* __restrict__ outf, float* __restrict__ outf1,
             const float* __restrict__ rs, const float* __restrict__ rs1,
             u16* __restrict__ Pcq, u16* __restrict__ Pqc,
             float* __restrict__ rowsum) {
  __shared__ __align__(16) u16 sA[256 * 64];
  __shared__ __align__(16) u16 sB[128 * 64];
  const int tid = threadIdx.x;
  const int lane = tid & 63;
  const int wave = tid >> 6;
  const int wr = (wave >> 1) * 64;
  const int wc = (wave & 1) * 64;
  const int by = blockIdx.y, bx = blockIdx.x;
  const int z = blockIdx.z;

  f32x4 acc[4][4];
#pragma unroll
  for (int i = 0; i < 4; ++i)
#pragma unroll
    for (int j = 0; j < 4; ++j) acc[i][j] = f32x4{0.f, 0.f, 0.f, 0.f};

  kloop((z ? A1 : A) + (size_t)(by * 256) * lda,
        (z ? B1 : B) + (size_t)(bx * 128) * ldb,
        lda, ldb, K, sA, sB, tid, wr, wc, acc);

  const int qr = (lane >> 4) * 4;
  const int qc = lane & 15;

  if constexpr (EPI == 1) {
    const bool top = (by < 16);
    const bool left = (bx < 32);
    u16* pdst = nullptr;
    if (top && !left) pdst = Pcq;
    if (!top && left) pdst = Pqc;
    const int growb = by * 256 + wr;
    const int rbase = growb - (top ? 0 : 4096);
    const int cbase = bx * 128 + wc - (left ? 0 : 4096);
#pragma unroll
    for (int tm = 0; tm < 4; ++tm) {
      float e[4][4];
      float rsum[4] = {0.f, 0.f, 0.f, 0.f};
#pragma unroll
      for (int tn = 0; tn < 4; ++tn)
#pragma unroll
        for (int r = 0; r < 4; ++r) {
          e[tn][r] = exp2_hw(acc[tm][tn][r]);  // scores pre-scaled by log2(e)
          rsum[r] += e[tn][r];
        }
#pragma unroll
      for (int r = 0; r < 4; ++r) {
        float v = rsum[r];
        v += __shfl_xor(v, 1);
        v += __shfl_xor(v, 2);
        v += __shfl_xor(v, 4);
        v += __shfl_xor(v, 8);
        if ((lane & 15) == 0)
          atomicAdd(&rowsum[growb + tm * 16 + qr + r], v);
      }
      if (pdst) {
#pragma unroll
        for (int tn = 0; tn < 4; ++tn)
#pragma unroll
          for (int r = 0; r < 4; ++r) {
            int row = rbase + tm * 16 + qr + r;
            pdst[(size_t)row * 4096 + cbase + tn * 16 + qc] = f2b(e[tn][r]);
          }
      }
    }
  } else {  // EPI 4: PV -> fp32 d_out, divided by rowsum
    float* of = z ? outf1 : outf;
    const float* rsz = z ? rs1 : rs;
#pragma unroll
    for (int tm = 0; tm < 4; ++tm)
#pragma unroll
      for (int r = 0; r < 4; ++r) {
        int row = by * 256 + wr + tm * 16 + qr + r;
        float inv = 1.0f / rsz[row];
#pragma unroll
        for (int tn = 0; tn < 4; ++tn) {
          int col = bx * 128 + wc + tn * 16 + qc;
          of[(size_t)row * ldc + col] = acc[tm][tn][r] * inv;
        }
      }
  }
}

// ---------------- launcher ----------------

extern "C" void kernel_launch(void* const* d_in, const int* in_sizes, int n_in,
                              void* d_out, int out_size, void* d_ws, size_t ws_size,
                              hipStream_t stream) {
  (void)in_sizes; (void)n_in; (void)out_size; (void)ws_size;
  const float* query = (const float*)d_in[0];
  const float* s     = (const float*)d_in[1];
  const float* tg    = (const float*)d_in[2];
  const float* Wqkv  = (const float*)d_in[3];
  const float* Wps   = (const float*)d_in[4];
  const float* Wpq   = (const float*)d_in[5];
  float* out = (float*)d_out;

  char* ws = (char*)d_ws;
  u16* cB     = (u16*)ws; ws += (size_t)8192 * 1024 * 2;   // [s+tg ; query] bf16
  u16* sBf    = (u16*)ws; ws += (size_t)4096 * 1024 * 2;   // s bf16
  u16* qks    = (u16*)ws; ws += (size_t)8192 * 2048 * 2;   // [q*SCALE*LOG2E | k*SCALE]
  u16* WqkB   = (u16*)ws; ws += (size_t)2048 * 1024 * 2;
  u16* WpsB   = (u16*)ws; ws += (size_t)1024 * 1024 * 2;
  u16* WpqB   = (u16*)ws; ws += (size_t)1024 * 1024 * 2;
  u16* VsT    = (u16*)ws; ws += (size_t)1024 * 4096 * 2;   // Wps@query^T
  u16* VqT    = (u16*)ws; ws += (size_t)1024 * 4096 * 2;   // Wpq@s^T
  u16* Pcq    = (u16*)ws; ws += (size_t)4096 * 4096 * 2;
  u16* Pqc    = (u16*)ws; ws += (size_t)4096 * 4096 * 2;
  float* rowsum = (float*)ws;  // 8192 floats

  const u16* qBf = cB + (size_t)4096 * 1024;  // query bf16 rows of cB

  const float SCALE = 0.17677669529663687f;   // 1024^-0.25
  const float LOG2E = 1.4426950408889634f;

  prep_all<<<6152, 256, 0, stream>>>(query, s, tg, Wqkv, Wps, Wpq,
                                     cB, sBf, WqkB, WpsB, WpqB, rowsum);
  // merged GEMM1 + V'^T pair (768 blocks of 512 thr)
  gemm_qkv<<<768, 512, 0, stream>>>(cB, WqkB, qks, WpsB, WpqB, qBf, sBf,
                                    VsT, VqT, SCALE * LOG2E, SCALE);
  // GEMM2: scores (8192x8192) -> 2^score quadrants (bf16) + row sums
  gemm_bt<1><<<dim3(64, 32), 512, 0, stream>>>(
      qks, nullptr, qks + 1024, nullptr, 2048, 2048, 1024, 0,
      nullptr, nullptr, nullptr, nullptr, Pcq, Pqc, rowsum);
  // PV (z-batched), fp32 straight to d_out
  gemm_bt<4><<<dim3(8, 16, 2), 512, 0, stream>>>(
      Pcq, Pqc, VsT, VqT, 4096, 4096, 4096, 1024,
      out, out + (size_t)4096 * 1024, rowsum, rowsum + 4096,
      nullptr, nullptr, nullptr);
}